// Round 5
// baseline (125.306 us; speedup 1.0000x reference)
//
#include <hip/hip_runtime.h>
#include <hip/hip_fp16.h>
#include <stdint.h>

#define T_LEN 262144
#define S 64
#define SP1 65

// forward: L=32 outputs + W=4 warm-up, ONE chain per wave (TLP > ILP:
// R3 measured 2 chains/wave at SAME wave count ~7us slower; rolled loops
// no better). 8192 chains -> 2048 blocks of 256 -> 8 blocks/CU.
#define L_FWD 32
#define W_FWD 4
#define C_FWD (T_LEN / L_FWD)    // 8192 chunks
#define C_PER_XCD (C_FWD / 8)    // 1024 chunks per XCD slice

// level-1 seed chase: W1 chunk-boundaries per thread, V1 warm chunk-hops
// (V1=4 chunk maps = 128 composed bp steps of convergence margin).
#define W1 4
#define V1 4

// level-2: one wave per TWO chunks; bp staged to LDS (coalesced), chase
// runs on LDS. 4096 waves -> 1024 blocks of 256.
#define K2B_BLOCKS (C_FWD / 8)

// workspace layout
#define WS_BP_OFF 2048
#define WS_SKIP_OFF (WS_BP_OFF + 16 * 1024 * 1024)   // 512 KB chunk maps
#define WS_SEED_OFF (WS_SKIP_OFF + 512 * 1024)       // 8 KB boundary seeds

// DPP cumulative u32-min step (old = own value, bound_ctrl=false). After
// shr1,2,4,8 + bcast15 + bcast31, lane 63 holds the wave-wide min.
template <int CTRL>
__device__ __forceinline__ unsigned int dpp_umin_step(unsigned int v) {
    unsigned int t = (unsigned int)__builtin_amdgcn_update_dpp(
        (int)v, (int)v, CTRL, 0xf, 0xf, false);
    return min(t, v);
}

__device__ __forceinline__ float readlane_f(float v, int lane) {
    return __int_as_float(__builtin_amdgcn_readlane(__float_as_int(v), lane));
}

// packed argmax key: all scores < 0 -> u32-min on raw bits == float-max;
// low 6 bits carry j, tie-break = first occurrence (smaller j).
__device__ __forceinline__ unsigned int pack_key(float a, int j) {
    return (__float_as_uint(a) & 0xFFFFFFC0u) | (unsigned)j;
}

// k1: chunked forward Viterbi -- step loop is byte-identical to the
// R0-proven 43.5us form (NO ds ops added inside the loop; R4 measured
// that an in-loop ds_bpermute serializes with strans reads via lgkmcnt).
// Chunk map composed POST-LOOP from register-resident pk[] bytes (static
// indices), 32 serial bpermutes ~2.2Kcy once per chunk (~2% of wall).
// skipT[c*64+s] = state at t=c*32-1 given state s at t=c*32+31.
__global__ __launch_bounds__(256, 8) void k1_forward(
    const int* __restrict__ rolls, const float* __restrict__ trans,
    const float* __restrict__ ll,
    unsigned int* __restrict__ bp4, unsigned char* __restrict__ skipT,
    int* __restrict__ wsFinal, float* __restrict__ out_score) {
    __shared__ __half strans_h[S * S];  // strans_h[j*64 + i] = trans[i][j]
    __shared__ float srowmin[S];
    __shared__ float sMc[S];
    const int tid = threadIdx.x;
    const int lane = tid & 63;
    const int wv = tid >> 6;

    if (blockIdx.x == 0 && tid == 0)
        out_score[0] = 0.0f;  // k2b is stream-ordered after k1 -> safe

    for (int k = tid; k < S * S; k += 256)
        strans_h[k] = __float2half(trans[(k & 63) * SP1 + (k >> 6)]);
    __syncthreads();

    // per-block Mc: rowmin_i = min_j trans[i][j]; Mc[j] = min_i(rowmin_i - trans[i][j])
    {
        int i = tid >> 2, q = tid & 3;
        float mn = 3.0e38f;
        #pragma unroll
        for (int u = 0; u < 16; ++u)
            mn = fminf(mn, __half2float(strans_h[((q * 16 + u) << 6) | i]));
        mn = fminf(mn, __shfl_xor(mn, 1));
        mn = fminf(mn, __shfl_xor(mn, 2));
        if (q == 0) srowmin[i] = mn;
    }
    __syncthreads();
    {
        int j = tid >> 2, q = tid & 3;
        float mc = 3.0e38f;
        #pragma unroll
        for (int u = 0; u < 16; ++u) {
            int i = q * 16 + u;
            mc = fminf(mc, srowmin[i] - __half2float(strans_h[(j << 6) | i]));
        }
        mc = fminf(mc, __shfl_xor(mc, 1));
        mc = fminf(mc, __shfl_xor(mc, 2));
        if (q == 0) sMc[j] = mc;
    }
    __syncthreads();
    const float mcol = sMc[lane];

    // XCD-grouped chunk id: XCD x = g%8 handles chunks x*C_PER_XCD + ...
    const int c = (blockIdx.x & 7) * C_PER_XCD + (blockIdx.x >> 3) * 4 + wv;
    const int beg_out = c * L_FWD;
    int t0 = beg_out - W_FWD;
    if (t0 < 1) t0 = 1;

    // rolls for the whole chunk (plus prefetch slack) in one VGPR
    int vroll = rolls[min(t0 + lane, T_LEN - 1)];

    float delta;
    if (c == 0) {
        delta = trans[lane * SP1 + S] + ll[rolls[0] * S + lane];  // exact init
    } else {
        delta = 0.0f;  // arbitrary; warm-up coalesces (up to additive const)
    }

    // ll pipeline: ll_cur for step t, ll_nxt for t+1; issue t+2 in-loop
    int r0 = __builtin_amdgcn_readlane(vroll, 0);
    int r1 = __builtin_amdgcn_readlane(vroll, 1);
    float ll_cur = ll[r0 * S + lane];
    float ll_nxt = ll[r1 * S + lane];

    int idx = 0;  // t - t0

    auto step = [&]() -> unsigned int {
        int rp = __builtin_amdgcn_readlane(vroll, idx + 2);
        float ll_new = ll[rp * S + lane];  // used at t+2

        float cvec = delta + ll_cur;  // < 0 always

        // one packed u32-min reduce -> wave max value AND its lane id
        unsigned int kv = pack_key(cvec, lane);
        kv = dpp_umin_step<0x111>(kv);
        kv = dpp_umin_step<0x112>(kv);
        kv = dpp_umin_step<0x114>(kv);
        kv = dpp_umin_step<0x118>(kv);
        kv = dpp_umin_step<0x142>(kv);
        kv = dpp_umin_step<0x143>(kv);
        unsigned int kmin =
            (unsigned int)__builtin_amdgcn_readlane((int)kv, 63);

        const int jm = (int)(kmin & 63u);
        // leader column unconditionally; threshold from REGISTER Mc.
        // cmax_q <= cmax -> conservative -> survivor superset of winners.
        float h0 = __half2float(strans_h[(jm << 6) | lane]);
        float cjm = readlane_f(cvec, jm);
        float thr = __uint_as_float(kmin & 0xFFFFFFC0u) + mcol;
        unsigned int m = pack_key(h0 + cjm, jm);

        unsigned long long mask = __ballot(cvec >= thr) & ~(1ull << jm);
        if (mask) {  // wave-uniform; ~1 extra survivor typical
            int j1 = __ffsll(mask) - 1;
            unsigned long long rm = mask & (mask - 1);
            float a1 = __half2float(strans_h[(j1 << 6) | lane]) +
                       readlane_f(cvec, j1);
            m = min(m, pack_key(a1, j1));
            while (rm) {  // rare (>2 survivors)
                int j = __ffsll(rm) - 1;
                rm &= (rm - 1);
                float a = __half2float(strans_h[(j << 6) | lane]) +
                          readlane_f(cvec, j);
                m = min(m, pack_key(a, j));
            }
        }

        delta = __uint_as_float(m & 0xFFFFFFC0u);  // quantized (~2^-15 rel)
        ll_cur = ll_nxt;
        ll_nxt = ll_new;
        ++idx;
        return m;
    };

    // warm-up: exactly W_FWD steps for c>0 (c==0 starts exact at t=1)
    if (c != 0) {
        #pragma unroll
        for (int w = 0; w < W_FWD; ++w)
            (void)step();
    }

    // main: 8 packed dwords accumulated in registers; burst store at end
    const int qb = beg_out >> 2;
    unsigned int pk[8];
    {   // q = 0: c==0 covers t=1..3 only (byte 0 never read by backtrack)
        unsigned int p = 0u;
        int u0 = (c == 0) ? 1 : 0;
        for (int u = u0; u < 4; ++u) {
            unsigned int m = step();
            p = (p >> 8) | ((m & 63u) << 24);
        }
        pk[0] = p;
    }
    #pragma unroll
    for (int q = 1; q < 8; ++q) {
        unsigned int p = 0u;
        #pragma unroll
        for (int u = 0; u < 4; ++u) {
            unsigned int m = step();
            p = (p >> 8) | ((m & 63u) << 24);
        }
        pk[q] = p;
    }
    #pragma unroll
    for (int q = 0; q < 8; ++q)
        bp4[(unsigned)((qb + q) << 6) | (unsigned)lane] = pk[q];

    // post-loop chunk-map composition from register-resident bp bytes
    // (static pk indices; vmap only feeds the bpermute ADDRESS).
    // Invariant: vmap[lane] = s_{t_first-1} given s_t = lane after
    // composing step t:  vmap' = vmap[ bp_t[lane] ].
    {
        const int u00 = (c == 0) ? 1 : 0;  // byte 0 of pk[0] unused for c==0
        int vmap = (int)((pk[0] >> (u00 << 3)) & 63u);
        for (int u = u00 + 1; u < 4; ++u) {
            int bp = (int)((pk[0] >> (u << 3)) & 63u);
            vmap = __builtin_amdgcn_ds_bpermute(bp << 2, vmap);
        }
        #pragma unroll
        for (int q = 1; q < 8; ++q) {
            #pragma unroll
            for (int u = 0; u < 4; ++u) {
                int bp = (int)((pk[q] >> (u << 3)) & 63u);
                vmap = __builtin_amdgcn_ds_bpermute(bp << 2, vmap);
            }
        }
        // state at t=c*32-1 given state lane at t=c*32+31
        skipT[(c << 6) | lane] = (unsigned char)vmap;
    }

    if (c == C_FWD - 1) {
        float fmx = delta;
        for (int off = 32; off; off >>= 1)
            fmx = fmaxf(fmx, __shfl_xor(fmx, off));
        unsigned long long em = __ballot(delta == fmx);
        if (lane == 0)
            *wsFinal = __ffsll(em) - 1;
    }
}

// k2a: chunk-boundary seeds. Thread w owns boundaries c in [w*W1, w*W1+W1);
// chases from te = chi+V1 (exact wsFinal seed for the tail thread, V1=4
// composed chunk-maps = 128 bp steps of convergence otherwise), recording
// Bseed[c] = state at t = c*32+31.
__global__ __launch_bounds__(256) void k2a_seed(
    const unsigned char* __restrict__ skipT, const int* __restrict__ wsFinal,
    unsigned char* __restrict__ Bseed) {
    int w = blockIdx.x * 256 + threadIdx.x;  // 0 .. C_FWD/W1-1
    int clo = w * W1;
    int chi = clo + W1 - 1;
    int te = chi + V1;
    int s;
    if (te >= C_FWD - 1) {
        te = C_FWD - 1;
        s = *wsFinal;  // exact
    } else {
        s = 0;         // arbitrary; chunk-map chase coalesces
    }
    #pragma unroll
    for (int u = 0; u < W1 + V1; ++u) {
        int c = te - u;
        if (c >= clo) {
            if (c <= chi) Bseed[c] = (unsigned char)s;
            s = (int)skipT[(c << 6) | s];  // B_{c-1} = M_c[B_c]
        }
    }
}

// k2b: one wave per TWO chunks. Stage both chunks' bp (4 KB) into LDS with
// 16 COALESCED dword loads (16 MiB total streamed at full BW -- replaces
// the old 491K scattered 4B gathers = ~31MB of random 64B lines), then all
// lanes chase 32 dependent LDS hops from the EXACT Bseed (no warm-up).
// Lane k of each 32-lane group captures s_t for its t; path write + exact
// fp32 scoring; one atomic per block.
__global__ __launch_bounds__(256) void k2b_backtrack(
    const unsigned int* __restrict__ bp4, const unsigned char* __restrict__ Bseed,
    const int* __restrict__ rolls, const float* __restrict__ trans,
    const float* __restrict__ ll, float* __restrict__ out_path,
    float* __restrict__ out_score) {
    __shared__ unsigned int sbp[4 * 1024];  // 4 waves x 2 chunks x 512 dwords
    __shared__ float spart[4];
    const int tid = threadIdx.x;
    const int lane = tid & 63;
    const int wv = tid >> 6;
    // chunk-group g matched to k1's XCD slice: block B (XCD B%8) reads
    // chunks [(B%8)*1024 + (B>>3)*8, ... +8)
    const int g = (blockIdx.x & 7) * (K2B_BLOCKS / 8) + (blockIdx.x >> 3);
    const int cA = g * 8 + wv * 2;       // this wave: chunks cA, cA+1
    const int grp = lane >> 5;           // 0 -> cA, 1 -> cA+1
    const int k = lane & 31;
    const int c = cA + grp;

    // stage: 16 rows (quads) x 64 dwords, fully coalesced
    unsigned int* wbase = sbp + (wv << 10);
    #pragma unroll
    for (int r = 0; r < 16; ++r)
        wbase[(r << 6) | lane] = bp4[(unsigned)(((cA * 8 + r) << 6) | lane)];
    __syncthreads();

    int s = (int)Bseed[c];  // exact state at t = c*32+31
    int cap = 0;
    const char* cbase = (const char*)(wbase + (grp << 9));
    #pragma unroll
    for (int d = 31; d >= 0; --d) {
        cap = (d == k) ? s : cap;  // capture s_{c*32+d} for lane k==d
        s = (int)(unsigned char)
                cbase[((d >> 2) << 8) + (s << 2) + (d & 3)];  // -> s_{t-1}
    }
    // now s = s_{c*32-1}; cap = s_t for t = c*32+k
    int spv = __shfl_up(cap, 1);  // s_{t-1} from lane k-1
    if (k == 0) spv = s;

    const int t = c * 32 + k;
    out_path[T_LEN - 1 - t] = (float)cap;

    int rt = rolls[t];
    float acc;
    if (t == 0)  // init term (chunk 0, lane k=0): no transition term at t=0
        acc = trans[cap * SP1 + S] + ll[rt * S + cap];
    else
        acc = trans[cap * SP1 + spv] + ll[rt * S + spv];

    for (int off = 32; off; off >>= 1)
        acc += __shfl_xor(acc, off);
    if (lane == 0) spart[wv] = acc;
    __syncthreads();
    if (tid == 0)
        atomicAdd(out_score, (spart[0] + spart[1]) + (spart[2] + spart[3]));
}

extern "C" void kernel_launch(void* const* d_in, const int* in_sizes, int n_in,
                              void* d_out, int out_size, void* d_ws, size_t ws_size,
                              hipStream_t stream) {
    const int* rolls = (const int*)d_in[0];
    const float* trans = (const float*)d_in[1];   // (64, 65)
    const float* ll = (const float*)d_in[2];      // (128, 64)
    float* out = (float*)d_out;                   // [0..T): path (reverse), [T]: score
    char* ws = (char*)d_ws;
    int* wsFinal = (int*)(ws + 8);
    unsigned int* bp4 = (unsigned int*)(ws + WS_BP_OFF);       // 16 MiB packed bp
    unsigned char* skipT = (unsigned char*)(ws + WS_SKIP_OFF); // 512 KB chunk maps
    unsigned char* Bseed = (unsigned char*)(ws + WS_SEED_OFF); // 8 KB seeds

    k1_forward<<<C_FWD / 4, 256, 0, stream>>>(rolls, trans, ll, bp4, skipT,
                                              wsFinal, out + T_LEN);
    k2a_seed<<<C_FWD / W1 / 256, 256, 0, stream>>>(skipT, wsFinal, Bseed);
    k2b_backtrack<<<K2B_BLOCKS, 256, 0, stream>>>(bp4, Bseed, rolls, trans, ll,
                                                  out, out + T_LEN);
}

// Round 6
// 121.095 us; speedup vs baseline: 1.0348x; 1.0348x over previous
//
#include <hip/hip_runtime.h>
#include <hip/hip_fp16.h>
#include <stdint.h>

#define T_LEN 262144
#define S 64
#define SP1 65

// forward: L=32 outputs + W=4 warm-up, ONE chain per wave (TLP > ILP:
// R3 measured 2 chains/wave at SAME wave count ~7us slower).
// 8192 chains -> 2048 blocks of 256 -> 8 blocks/CU.
#define L_FWD 32
#define W_FWD 4
#define C_FWD (T_LEN / L_FWD)   // 8192
#define C_PER_XCD (C_FWD / 8)   // 1024 chunks per XCD slice

// backtrack: one THREAD per window. LB=8 outputs, VB=8 warm chase.
// (R2-measured ~21.6us; LB=4 regressed ~+8us in R1 -- do not touch.)
#define LB2 8
#define VB2 8
#define NW (T_LEN / LB2)        // 32768 windows -> 128 blocks of 256
#define PITCH (LB2 + 2)

#define WS_D_OFF (2048 + 16 * 1024 * 1024)  // D table after bp4

// DPP cumulative u32-min step (old = own value, bound_ctrl=false). After
// shr1,2,4,8 + bcast15 + bcast31, lane 63 holds the wave-wide min.
template <int CTRL>
__device__ __forceinline__ unsigned int dpp_umin_step(unsigned int v) {
    unsigned int t = (unsigned int)__builtin_amdgcn_update_dpp(
        (int)v, (int)v, CTRL, 0xf, 0xf, false);
    return min(t, v);
}

__device__ __forceinline__ float readlane_f(float v, int lane) {
    return __int_as_float(__builtin_amdgcn_readlane(__float_as_int(v), lane));
}

// packed argmax key: all scores < 0 -> u32-min on raw bits == float-max;
// low 6 bits carry j, tie-break = first occurrence (smaller j).
__device__ __forceinline__ unsigned int pack_key(float a, int j) {
    return (__float_as_uint(a) & 0xFFFFFFC0u) | (unsigned)j;
}

// k0: build D[jm][j] = min_i( h(trans[i][jm]) - h(trans[i][j]) ), h = fp16
// quantization (the SAME values k1's update uses -> bound exact for the
// computation done). Stored fp16 rounded toward -inf (conservative).
// j can win some row only if c_j >= c_jm + D[jm][j]; window ~-0.32 vs
// Mc's ~-0.55 -> expected survivor cut ~7 -> ~3.
__global__ __launch_bounds__(256) void k0_mkD(const float* __restrict__ trans,
                                              __half* __restrict__ Dg) {
    int p = blockIdx.x * 256 + threadIdx.x;  // 0..4095
    int jm = p >> 6, j = p & 63;
    float d = 3.0e38f;
    #pragma unroll 8
    for (int i = 0; i < S; ++i) {
        float a = __half2float(__float2half(trans[i * SP1 + jm]));
        float b = __half2float(__float2half(trans[i * SP1 + j]));
        d = fminf(d, a - b);  // exact in fp32 (11-bit operands)
    }
    __half h = __float2half(d);
    if (__half2float(h) > d) {  // nudge toward -inf
        unsigned short u = __half_as_ushort(h);
        u = (u & 0x8000) ? (unsigned short)(u + 1)
                         : (u ? (unsigned short)(u - 1) : (unsigned short)0x8001);
        h = __ushort_as_half(u);
    }
    Dg[p] = h;
}

// k1: chunked forward Viterbi, one chain per wave, 4 chains/block.
// R2 structure verbatim; ONLY change: survivor threshold uses the tight
// D bound (sD[jm*64+lane], read at the same dependency depth as the
// leader column h0 -> no added critical path), replacing the loose Mc.
// XCD-swizzled chunk ownership retained (R2-neutral, kept for min-diff).
__global__ __launch_bounds__(256, 8) void k1_forward(
    const int* __restrict__ rolls, const float* __restrict__ trans,
    const float* __restrict__ ll, const __half* __restrict__ Dg,
    unsigned int* __restrict__ bp4, int* __restrict__ wsFinal,
    float* __restrict__ out_score) {
    __shared__ __half strans_h[S * S];  // strans_h[j*64 + i] = trans[i][j]
    __shared__ __half sD[S * S];        // sD[jm*64 + j] = D[jm][j]
    const int tid = threadIdx.x;
    const int lane = tid & 63;
    const int wv = tid >> 6;

    if (blockIdx.x == 0 && tid == 0)
        out_score[0] = 0.0f;  // k2 is stream-ordered after k1 -> safe

    for (int k = tid; k < S * S; k += 256)
        strans_h[k] = __float2half(trans[(k & 63) * SP1 + (k >> 6)]);
    for (int k = tid; k < (S * S) / 2; k += 256)
        ((unsigned int*)sD)[k] = ((const unsigned int*)Dg)[k];
    __syncthreads();

    // XCD-grouped chunk id: XCD x = g%8 handles chunks x*C_PER_XCD + ...
    const int c = (blockIdx.x & 7) * C_PER_XCD + (blockIdx.x >> 3) * 4 + wv;
    const int beg_out = c * L_FWD;
    int t0 = beg_out - W_FWD;
    if (t0 < 1) t0 = 1;

    // rolls for the whole chunk (plus prefetch slack) in one VGPR
    int vroll = rolls[min(t0 + lane, T_LEN - 1)];

    float delta;
    if (c == 0) {
        delta = trans[lane * SP1 + S] + ll[rolls[0] * S + lane];  // exact init
    } else {
        delta = 0.0f;  // arbitrary; warm-up coalesces (up to additive const)
    }

    // ll pipeline: ll_cur for step t, ll_nxt for t+1; issue t+2 in-loop
    int r0 = __builtin_amdgcn_readlane(vroll, 0);
    int r1 = __builtin_amdgcn_readlane(vroll, 1);
    float ll_cur = ll[r0 * S + lane];
    float ll_nxt = ll[r1 * S + lane];

    int idx = 0;  // t - t0

    auto step = [&]() -> unsigned int {
        int rp = __builtin_amdgcn_readlane(vroll, idx + 2);
        float ll_new = ll[rp * S + lane];  // used at t+2

        float cvec = delta + ll_cur;  // < 0 always

        // one packed u32-min reduce -> wave max value AND its lane id
        unsigned int kv = pack_key(cvec, lane);
        kv = dpp_umin_step<0x111>(kv);
        kv = dpp_umin_step<0x112>(kv);
        kv = dpp_umin_step<0x114>(kv);
        kv = dpp_umin_step<0x118>(kv);
        kv = dpp_umin_step<0x142>(kv);
        kv = dpp_umin_step<0x143>(kv);
        unsigned int kmin =
            (unsigned int)__builtin_amdgcn_readlane((int)kv, 63);

        const int jm = (int)(kmin & 63u);
        // leader column + D column: both LDS reads share jm's dependency
        // depth and issue together. cmax_q <= c_jm and D_rd <= D_true ->
        // threshold conservative -> survivor superset of all row winners.
        float h0 = __half2float(strans_h[(jm << 6) | lane]);
        float dcol = __half2float(sD[(jm << 6) | lane]);
        float cjm = readlane_f(cvec, jm);
        float thr = __uint_as_float(kmin & 0xFFFFFFC0u) + dcol;
        unsigned int m = pack_key(h0 + cjm, jm);

        unsigned long long mask = __ballot(cvec >= thr) & ~(1ull << jm);
        if (mask) {  // wave-uniform; ~1-3 extra survivors expected
            int j1 = __ffsll(mask) - 1;
            unsigned long long rm = mask & (mask - 1);
            float a1 = __half2float(strans_h[(j1 << 6) | lane]) +
                       readlane_f(cvec, j1);
            m = min(m, pack_key(a1, j1));
            while (rm) {
                int j = __ffsll(rm) - 1;
                rm &= (rm - 1);
                float a = __half2float(strans_h[(j << 6) | lane]) +
                          readlane_f(cvec, j);
                m = min(m, pack_key(a, j));
            }
        }

        delta = __uint_as_float(m & 0xFFFFFFC0u);  // quantized (~2^-15 rel)
        ll_cur = ll_nxt;
        ll_nxt = ll_new;
        ++idx;
        return m;
    };

    // warm-up: exactly W_FWD steps for c>0 (c==0 starts exact at t=1)
    if (c != 0) {
        #pragma unroll
        for (int w = 0; w < W_FWD; ++w)
            (void)step();
    }

    // main: 8 packed dwords accumulated in registers; burst store at end
    const int qb = beg_out >> 2;
    unsigned int pk[8];
    {   // q = 0: c==0 covers t=1..3 only (byte 0 never read by backtrack)
        unsigned int p = 0u;
        int u0 = (c == 0) ? 1 : 0;
        for (int u = u0; u < 4; ++u) {
            unsigned int m = step();
            p = (p >> 8) | ((m & 63u) << 24);
        }
        pk[0] = p;
    }
    #pragma unroll
    for (int q = 1; q < 8; ++q) {
        unsigned int p = 0u;
        #pragma unroll
        for (int u = 0; u < 4; ++u) {
            unsigned int m = step();
            p = (p >> 8) | ((m & 63u) << 24);
        }
        pk[q] = p;
    }
    #pragma unroll
    for (int q = 0; q < 8; ++q)
        bp4[(unsigned)((qb + q) << 6) | (unsigned)lane] = pk[q];

    if (c == C_FWD - 1) {
        float fmx = delta;
        for (int off = 32; off; off >>= 1)
            fmx = fmaxf(fmx, __shfl_xor(fmx, off));
        unsigned long long em = __ballot(delta == fmx);
        if (lane == 0)
            *wsFinal = __ffsll(em) - 1;
    }
}

// k2: R2 verbatim (measured ~21.6us). One THREAD per window; 15 dependent
// gathers from te=thi+VB2; path write + exact fp32 scoring with
// neighbor-stitched boundary; one atomic per block.
__global__ __launch_bounds__(256) void k2_backtrack(
    const unsigned int* __restrict__ bp4, const int* __restrict__ wsFinal,
    const int* __restrict__ rolls, const float* __restrict__ trans,
    const float* __restrict__ ll, float* __restrict__ out_path,
    float* __restrict__ out_score) {
    __shared__ int sst[256 * PITCH];
    __shared__ float spart[4];
    const int tid = threadIdx.x;
    // XCD-matched window group: g = (B%8)*16 + B/8 (bijective for B<128)
    const int grp = (blockIdx.x & 7) * 16 + (blockIdx.x >> 3);
    const int b = grp * 256 + tid;          // window id
    const int tlo = b * LB2;
    const int thi = tlo + LB2 - 1;
    int te = thi + VB2;
    int s;
    if (te >= T_LEN - 1) {
        te = T_LEN - 1;
        s = *wsFinal;   // exact seed for the tail windows
    } else {
        s = 0;          // arbitrary; chase coalesces
    }
    int* row = sst + tid * PITCH;
    #pragma unroll
    for (int u = 0; u < LB2 + VB2 - 1; ++u) {  // 15 dependent gathers max
        int t = te - u;
        if (t > tlo) {
            if (t <= thi + 1) row[t - tlo] = s;
            unsigned int w = bp4[((unsigned)(t >> 2) << 6) | (unsigned)s];
            s = (int)((w >> ((t & 3) << 3)) & 63u);
        }
    }
    row[0] = s;  // state at tlo
    __syncthreads();

    // path write: out[T-1-t] = s_t for t in [tlo, thi]
    #pragma unroll
    for (int u = 0; u < LB2; ++u)
        out_path[T_LEN - 1 - (tlo + u)] = (float)row[u];

    // score terms: t in [tlo+1, thi+1] (clamped to T-1):
    //   trans[s_t][s_{t-1}] + ll[rolls[t]][s_{t-1}]
    // boundary s_{thi+1}: neighbor thread's row[0]; tid==255 uses own
    // chase state at thi+1.
    float acc = 0.0f;
    #pragma unroll
    for (int u = 1; u <= LB2; ++u) {
        int t = tlo + u;
        if (t <= T_LEN - 1) {
            int sp = row[u - 1];
            int st = (u == LB2)
                         ? ((tid < 255) ? sst[(tid + 1) * PITCH] : row[LB2])
                         : row[u];
            acc += trans[st * SP1 + sp] + ll[rolls[t] * S + sp];
        }
    }
    if (b == 0) {  // init term
        int s0 = row[0];
        acc += trans[s0 * SP1 + S] + ll[rolls[0] * S + s0];
    }

    for (int off = 32; off; off >>= 1)
        acc += __shfl_xor(acc, off);
    if ((tid & 63) == 0) spart[tid >> 6] = acc;
    __syncthreads();
    if (tid == 0)
        atomicAdd(out_score, (spart[0] + spart[1]) + (spart[2] + spart[3]));
}

extern "C" void kernel_launch(void* const* d_in, const int* in_sizes, int n_in,
                              void* d_out, int out_size, void* d_ws, size_t ws_size,
                              hipStream_t stream) {
    const int* rolls = (const int*)d_in[0];
    const float* trans = (const float*)d_in[1];   // (64, 65)
    const float* ll = (const float*)d_in[2];      // (128, 64)
    float* out = (float*)d_out;                   // [0..T): path (reverse), [T]: score
    char* ws = (char*)d_ws;
    int* wsFinal = (int*)(ws + 8);
    unsigned int* bp4 = (unsigned int*)(ws + 2048); // 16 MiB packed bp
    __half* Dg = (__half*)(ws + WS_D_OFF);          // 8 KiB D table

    k0_mkD<<<16, 256, 0, stream>>>(trans, Dg);
    k1_forward<<<C_FWD / 4, 256, 0, stream>>>(rolls, trans, ll, Dg, bp4,
                                              wsFinal, out + T_LEN);
    k2_backtrack<<<NW / 256, 256, 0, stream>>>(bp4, wsFinal, rolls, trans, ll,
                                               out, out + T_LEN);
}